// Round 12
// baseline (209.907 us; speedup 1.0000x reference)
//
#include <hip/hip_runtime.h>
#include <hip/hip_bf16.h>
#include <stdint.h>

// Problem constants
#define Bn  4
#define Nn  10000
#define KRn 5
#define KAn 8
#define Cn  32
#define On  64
#define Kk  2
#define RN  8                  // rotations = KA
#define MT  32                 // points per block
#define NT  313                // tiles per batch = ceil(10000/32)
#define LDX 264                // LDS row stride (f16 elems): 256 + 8 pad

typedef __attribute__((ext_vector_type(8))) _Float16 f16x8;
typedef __attribute__((ext_vector_type(4))) _Float16 f16x4;
typedef __attribute__((ext_vector_type(4))) float f32x4;
typedef __attribute__((ext_vector_type(2))) float f32x2;
typedef __attribute__((ext_vector_type(4))) unsigned int u32x4;

// prep: (a) signal -> fp16 (gather hot-set 640 KB/batch), (b) summed
// un-rotated kernel wk (fp16, fragment layout), (c) bconst[o].
__global__ void prep_kernel(const float* __restrict__ signal,
                            const float* __restrict__ kernels,
                            const float* __restrict__ bias,
                            _Float16* __restrict__ wk,
                            float* __restrict__ bconst,
                            _Float16* __restrict__ sigh) {
  int tid = blockIdx.x * 256 + threadIdx.x;
  if (tid < (Bn * Nn * Cn) / 8) {
    const f32x4* s = (const f32x4*)(signal + (size_t)tid * 8);
    f32x4 v0 = s[0], v1 = s[1];
    f16x8 h;
    h[0] = (_Float16)v0.x; h[1] = (_Float16)v0.y;
    h[2] = (_Float16)v0.z; h[3] = (_Float16)v0.w;
    h[4] = (_Float16)v1.x; h[5] = (_Float16)v1.y;
    h[6] = (_Float16)v1.z; h[7] = (_Float16)v1.w;
    *(f16x8*)(sigh + (size_t)tid * 8) = h;
  }
  if (tid < KRn * KAn * 4 * 64) {
    int lane = tid & 63;
    int ot   = (tid >> 6) & 3;
    int q    = (tid >> 8) & 7;
    int p    = tid >> 11;
    int o  = ot * 16 + (lane & 15);
    int cb = (lane >> 4) * 8;
    const float* k0 = kernels + (((p * KAn + q) * On + o) * Cn + cb);
    const float* k1 = k0 + KRn * KAn * On * Cn;  // g=1
    f16x8 v;
#pragma unroll
    for (int j = 0; j < 8; ++j) v[j] = (_Float16)(k0[j] + k1[j]);
    *(f16x8*)(wk + (size_t)tid * 8) = v;
  }
  if (blockIdx.x == 0 && threadIdx.x < On) {
    float s = 0.f;
    for (int pq = 0; pq < KRn * KAn; ++pq) s += bias[pq * On + (int)threadIdx.x];
    bconst[threadIdx.x] = (float)Kk * s;
  }
}

// MT=32, batch-pinned XCD swizzle, bary one chunk ahead (regs->bs LDS),
// fp16 packed-half gather+interp -> xs, swapped-operand f16 MFMA (+setprio),
// dwordx4 epilogue.
__global__ __launch_bounds__(256, 4) void conv_kernel(
    const _Float16* __restrict__ sigh,
    const float* __restrict__ bary,
    const _Float16* __restrict__ wk,
    const float* __restrict__ bconst,
    float* __restrict__ out) {
  __shared__ __align__(16) _Float16 xs[MT * LDX];  // 16.5 KB
  __shared__ __align__(16) float bs[MT * 48];      // 6 KB

  // batch-pinned XCD swizzle: XCD = g%8 (round-robin); b = (g%8)/2 so each
  // XCD gathers ONE batch's 640 KB fp16 signal (stays L2-resident).
  const int g = blockIdx.x;
  const int b = (g & 7) >> 1;
  const int t = ((g >> 3) << 1) | (g & 1);
  if (t >= NT) return;
  const int m0 = t * MT;

  const int tid  = threadIdx.x;
  const int lane = tid & 63;
  const int wv   = tid >> 6;           // wave 0..3
  const int lm   = lane & 15;
  const int lg   = lane >> 4;
  const int sq   = lane >> 3;          // q of this 8-lane group
  const int cv   = lane & 7;           // channel-vec (4 ch) within row

  const _Float16* sigb = sigh + (size_t)b * Nn * Cn;
  const f16x8* wkf = reinterpret_cast<const f16x8*>(wk);

  // bary identity: thread (bpt, bc8) owns 6 floats of point bn, ring-slot bc8
  const int bpt = tid >> 3;            // 0..31
  const int bc8 = tid & 7;             // 0..7
  const int bn  = m0 + bpt;
  const bool bvalid = bn < Nn;
  const float* bybase = bary + (size_t)(b * Nn + bn) * 240 + bc8 * 6;

  f32x2 br0, br1, br2;

#define BR(PP) do {                                                            \
    if (bvalid) {                                                              \
      const float* s_ = bybase + (PP) * 48;                                    \
      br0 = *(const f32x2*)(s_);                                               \
      br1 = *(const f32x2*)(s_ + 2);                                           \
      br2 = *(const f32x2*)(s_ + 4);                                           \
    } else { br0 = (f32x2){0.f, 0.f}; br1 = br0; br2 = br0; }                  \
  } while (0)

#define BW() do {                                                              \
    float* d_ = &bs[bpt * 48 + bc8 * 6];                                       \
    *(f32x2*)(d_) = br0; *(f32x2*)(d_ + 2) = br1; *(f32x2*)(d_ + 4) = br2;     \
  } while (0)

  // stage current bs chunk -> xs: packed-half interp (no unpack/repack)
#define INTERP() do {                                                          \
    _Pragma("unroll")                                                          \
    for (int k = 0; k < 8; ++k) {                                              \
      int pt = k * 4 + wv;                                                     \
      const float* bb = &bs[pt * 48 + sq * 6];                                 \
      f32x2 p0 = *(const f32x2*)(bb);                                          \
      f32x2 p1 = *(const f32x2*)(bb + 2);                                      \
      f32x2 p2 = *(const f32x2*)(bb + 4);                                      \
      f16x4 a0 = *(const f16x4*)(sigb + (size_t)(int)p0.x * Cn + cv * 4);      \
      f16x4 a1 = *(const f16x4*)(sigb + (size_t)(int)p1.x * Cn + cv * 4);      \
      f16x4 a2 = *(const f16x4*)(sigb + (size_t)(int)p2.x * Cn + cv * 4);      \
      _Float16 w0 = (_Float16)p0.y, w1 = (_Float16)p1.y, w2 = (_Float16)p2.y;  \
      f16x4 v = a0 * (f16x4){w0, w0, w0, w0} + a1 * (f16x4){w1, w1, w1, w1}    \
              + a2 * (f16x4){w2, w2, w2, w2};                                  \
      *(f16x4*)(&xs[pt * LDX + sq * 32 + cv * 4]) = v;                         \
    }                                                                          \
  } while (0)

  f32x4 acc[2][2][4];                  // [rr][mt][ot] -> 64 acc regs
#pragma unroll
  for (int rr = 0; rr < 2; ++rr)
#pragma unroll
    for (int mt = 0; mt < 2; ++mt)
#pragma unroll
      for (int ot = 0; ot < 4; ++ot) acc[rr][mt][ot] = (f32x4){0.f, 0.f, 0.f, 0.f};

  // prologue: bary chunk 0 -> bs; stage chunk 0 -> xs
  BR(0); BW();
  __syncthreads();
  INTERP();

  for (int p = 0; p < KRn; ++p) {
    __syncthreads();                   // xs staged; bs free
    if (p < KRn - 1) BR(p + 1);        // HBM latency hides under GEMM

    // ---- GEMM chunk p: swapped operands, rotation-by-index ----
    __builtin_amdgcn_s_setprio(1);     // favor MFMA-phase waves (T5)
#pragma unroll
    for (int qp = 0; qp < 8; ++qp) {
      const f16x8* wp = wkf + (size_t)(p * 8 + qp) * 256 + lane;
      f16x8 Bf0 = wp[0], Bf1 = wp[64], Bf2 = wp[128], Bf3 = wp[192];
#pragma unroll
      for (int rr = 0; rr < 2; ++rr) {
        int q = (qp - (wv * 2 + rr)) & 7;  // chunk q feeds output ring r
#pragma unroll
        for (int mt = 0; mt < 2; ++mt) {
          f16x8 a = *(const f16x8*)(&xs[(mt * 16 + lm) * LDX + q * 32 + lg * 8]);
          acc[rr][mt][0] = __builtin_amdgcn_mfma_f32_16x16x32_f16(Bf0, a, acc[rr][mt][0], 0, 0, 0);
          acc[rr][mt][1] = __builtin_amdgcn_mfma_f32_16x16x32_f16(Bf1, a, acc[rr][mt][1], 0, 0, 0);
          acc[rr][mt][2] = __builtin_amdgcn_mfma_f32_16x16x32_f16(Bf2, a, acc[rr][mt][2], 0, 0, 0);
          acc[rr][mt][3] = __builtin_amdgcn_mfma_f32_16x16x32_f16(Bf3, a, acc[rr][mt][3], 0, 0, 0);
        }
      }
    }
    __builtin_amdgcn_s_setprio(0);

    if (p < KRn - 1) {
      BW();
      __syncthreads();                 // bs chunk p+1 visible
      INTERP();                        // stage chunk p+1 -> xs
    }
  }

  // ---- epilogue: D is o-in-register / n-in-lane -> dwordx4 row stores ----
  f32x4 bc4[4];
#pragma unroll
  for (int ot = 0; ot < 4; ++ot) bc4[ot] = *(const f32x4*)(bconst + ot * 16 + lg * 4);
#pragma unroll
  for (int rr = 0; rr < 2; ++rr) {
    int r = wv * 2 + rr;
#pragma unroll
    for (int mt = 0; mt < 2; ++mt) {
      int n = m0 + mt * 16 + lm;
      if (n < Nn) {
        float* rowp = out + (((size_t)b * RN + r) * Nn + n) * On;
#pragma unroll
        for (int ot = 0; ot < 4; ++ot) {
          f32x4 v = acc[rr][mt][ot] + bc4[ot];
          *(f32x4*)(rowp + ot * 16 + lg * 4) = v;
        }
      }
    }
  }
#undef BR
#undef BW
#undef INTERP
}

extern "C" void kernel_launch(void* const* d_in, const int* in_sizes, int n_in,
                              void* d_out, int out_size, void* d_ws, size_t ws_size,
                              hipStream_t stream) {
  const float* signal  = (const float*)d_in[0];
  const float* bary    = (const float*)d_in[1];
  const float* kernels = (const float*)d_in[2];
  const float* bias    = (const float*)d_in[3];
  float* out = (float*)d_out;

  // ws layout: wk (160 KB) | bconst (256 B) | sigh (2.56 MB)
  _Float16* wk = (_Float16*)d_ws;
  float* bconst = (float*)((char*)d_ws + 163840);
  _Float16* sigh = (_Float16*)((char*)d_ws + 164096);

  hipLaunchKernelGGL(prep_kernel, dim3(625), dim3(256), 0, stream,
                     signal, kernels, bias, wk, bconst, sigh);
  hipLaunchKernelGGL(conv_kernel, dim3(8 * 157), dim3(256), 0, stream,
                     sigh, bary, wk, bconst, out);
}